// Round 5
// baseline (3897.430 us; speedup 1.0000x reference)
//
#include <hip/hip_runtime.h>
#include <hip/hip_bf16.h>

// Problem constants
#define B_ 128
#define S_ 128
#define W_ 16
#define V_ 128
#define H_ 512
#define L_ 64

typedef _Float16 f16x8 __attribute__((ext_vector_type(8)));
typedef float f32x4 __attribute__((ext_vector_type(4)));

__device__ __forceinline__ float sigm(float v) { return 1.0f / (1.0f + __expf(-v)); }
__device__ __forceinline__ float tanhf_(float v) { return 1.0f - 2.0f / (1.0f + __expf(2.0f * v)); }

__device__ __forceinline__ unsigned short f16bits(_Float16 h) {
    return __builtin_bit_cast(unsigned short, h);
}

// System-scope fence: release/acquire visibility across XCDs (L2 writeback+inv).
__device__ __forceinline__ void fence_sys() { __threadfence_system(); }

// ---------------------------------------------------------------------------
// Workspace layout (bytes):
//   hbuf  u32 packed(hi16,lo16) [par2][dir2][128][512] @ 0        (1048576)
//   cnt   u32 [16]                                     @ 1048576  (64)
//   flag  i32                                          @ 1048640  (64)
//   x     u32 packed(hi16,lo16) [128][128][128]        @ 1048704  (8388608)
//   whalf f16 [1966080]                                @ 9437312  (3932160)
//         [whhf 786432 | whhb 786432 | wihf 196608 | wihb 196608]
//   smallF f32 [71745]                                 @ 13369472 (286980+pad)
//         [bihf 1536|bhhf 1536|bihb 1536|bhhb 1536|wlin 65536|blin 64|fg 1]
//   Ycat  f16 [128][128][1024]                         @ 13656576 (33554432)
//   total 47211008 bytes (~45 MB)
// ---------------------------------------------------------------------------
#define OFF_CNT   1048576
#define OFF_FLAG  1048640
#define OFF_X     1048704
#define OFF_WH    9437312
#define OFF_SMALL 13369472
#define OFF_YCAT  13656576

// Runtime input-dtype detection (insurance): low-16 exponent-field vote.
__global__ void detect_kernel(const unsigned* __restrict__ w, int* __restrict__ flag) {
    __shared__ int sv[256];
    int tid = threadIdx.x;
    unsigned word = w[tid];
    unsigned e = (word >> 7) & 0xFFu;
    sv[tid] = (e >= 64u && e <= 126u) ? 1 : 0;
    __syncthreads();
    for (int s = 128; s > 0; s >>= 1) {
        if (tid < s) sv[tid] += sv[tid + s];
        __syncthreads();
    }
    if (tid == 0) *flag = (sv[0] >= 160) ? 1 : 0;  // 1 = inputs are bf16
}

// Canonicalize the 4 big weight matrices into packed fp16 (RTN) in ws.
__global__ void prep_whalf(const void* __restrict__ whhf, const void* __restrict__ whhb,
                           const void* __restrict__ wihf, const void* __restrict__ wihb,
                           _Float16* __restrict__ dst, const int* __restrict__ flag) {
    int i = blockIdx.x * 256 + threadIdx.x;  // grid covers 1966080 exactly
    const void* src;
    int off;
    if (i < 786432)       { src = whhf; off = i; }
    else if (i < 1572864) { src = whhb; off = i - 786432; }
    else if (i < 1769472) { src = wihf; off = i - 1572864; }
    else                  { src = wihb; off = i - 1769472; }
    float v = (*flag) ? __bfloat162float(((const __hip_bfloat16*)src)[off])
                      : ((const float*)src)[off];
    dst[i] = (_Float16)v;
}

// Canonicalize biases + W_lin + b_lin + forget into fp32 in ws.
__global__ void prep_small(const void* __restrict__ bihf, const void* __restrict__ bhhf,
                           const void* __restrict__ bihb, const void* __restrict__ bhhb,
                           const void* __restrict__ wlin, const void* __restrict__ blin,
                           const void* __restrict__ fg,
                           float* __restrict__ dst, const int* __restrict__ flag) {
    int i = blockIdx.x * 256 + threadIdx.x;
    if (i >= 71745) return;
    const void* src;
    int off;
    if (i < 1536)       { src = bihf; off = i; }
    else if (i < 3072)  { src = bhhf; off = i - 1536; }
    else if (i < 4608)  { src = bihb; off = i - 3072; }
    else if (i < 6144)  { src = bhhb; off = i - 4608; }
    else if (i < 71680) { src = wlin; off = i - 6144; }
    else if (i < 71744) { src = blin; off = i - 71680; }
    else                { src = fg;   off = 0; }
    float v = (*flag) ? __bfloat162float(((const __hip_bfloat16*)src)[off])
                      : ((const float*)src)[off];
    dst[i] = v;
}

// FOFE: x[b,s,v] = sum_w (c==v) * forget^(#nonzero after w); store (hi,lo) fp16 pair.
__global__ void fofe_kernel(const int* __restrict__ chars,
                            const float* __restrict__ fg,
                            unsigned* __restrict__ xp) {
    __shared__ int cS[W_];
    int bi = blockIdx.x;  // b*S + s
    int tid = threadIdx.x;
    if (tid < W_) cS[tid] = chars[bi * W_ + tid];
    __syncthreads();
    float f = fg[0];
    float wt[W_];
    float cur = 1.0f;
#pragma unroll
    for (int w = W_ - 1; w >= 0; --w) {
        bool m = (cS[w] != 0);
        wt[w] = m ? cur : 0.0f;
        if (m) cur *= f;
    }
    int v = tid;  // blockDim = 128 = V_
    float acc = 0.0f;
#pragma unroll
    for (int w = 0; w < W_; ++w) acc += (cS[w] == v) ? wt[w] : 0.0f;
    _Float16 hi = (_Float16)acc;
    _Float16 lo = (_Float16)(acc - (float)hi);
    xp[(size_t)bi * V_ + v] = (unsigned)f16bits(hi) | ((unsigned)f16bits(lo) << 16);
}

// ---------------------------------------------------------------------------
// Persistent bidirectional GRU, fp16 hi/lo inputs, fp32 accumulate.
// Grid: 256 blocks x 128 threads, PLAIN launch (sync is hand-rolled atomics;
// grid == #CUs so all blocks are resident by capacity). chain = blockIdx>>4
// so a chain's 16 wgs are adjacent block IDs (robust to ordered dispatch);
// slice = blockIdx&15. Each wave owns 16 j x 3 gates; weights (single fp16)
// persistent in VGPRs. Cross-wg sync: per-chain monotonic atomic counter with
// system-scope fences (cross-XCD L2 non-coherence).
// ---------------------------------------------------------------------------
__launch_bounds__(128, 1)
__global__ void gru_kernel(const int* __restrict__ lengths,
                           const _Float16* __restrict__ wh,
                           const float* __restrict__ biasF,
                           const unsigned* __restrict__ xp,
                           unsigned* __restrict__ hbuf,
                           unsigned* __restrict__ cnt,
                           _Float16* __restrict__ Ycat) {
    constexpr int RSTR = 656;  // 640 + 16 pad halves
    __shared__ _Float16 Ahi[16 * RSTR];
    __shared__ _Float16 Alo[16 * RSTR];
    __shared__ int lenS[16];

    const int tid = threadIdx.x;
    const int wg = blockIdx.x;
    const int chain = wg >> 4;    // adjacent blocks form a chain
    const int js = wg & 15;       // 0..15 j-slice
    const int d = chain & 1;      // 0 fwd, 1 bwd
    const int bg = chain >> 1;    // 0..7
    const int b0 = bg * 16;
    const int wave = tid >> 6;
    const int lane = tid & 63;
    const int quad = lane >> 4;
    const int col = lane & 15;
    const int j0w = js * 32 + wave * 16;

    const _Float16* Whh = wh + (d ? 786432 : 0);
    const _Float16* Wih = wh + 1572864 + (d ? 196608 : 0);
    const float* bih = biasF + (d ? 3072 : 0);
    const float* bhh = biasF + 1536 + (d ? 3072 : 0);

    if (tid < 16) lenS[tid] = lengths[b0 + tid];
    __syncthreads();

    const int g_r = j0w + col;  // r row; z = 512+g_r; n = 1024+g_r

    // Persistent B fragments (single fp16): lane holds W[g][kk*32 + quad*8 + 0..7]
    f16x8 br[20], bz[20], bn[20];
#pragma unroll
    for (int kk = 0; kk < 16; ++kk) {
        int k = kk * 32 + quad * 8;
        br[kk] = *(const f16x8*)(Whh + (size_t)(g_r)*H_ + k);
        bz[kk] = *(const f16x8*)(Whh + (size_t)(512 + g_r) * H_ + k);
        bn[kk] = *(const f16x8*)(Whh + (size_t)(1024 + g_r) * H_ + k);
    }
#pragma unroll
    for (int kk = 16; kk < 20; ++kk) {
        int k = (kk - 16) * 32 + quad * 8;
        br[kk] = *(const f16x8*)(Wih + (size_t)(g_r)*V_ + k);
        bz[kk] = *(const f16x8*)(Wih + (size_t)(512 + g_r) * V_ + k);
        bn[kk] = *(const f16x8*)(Wih + (size_t)(1024 + g_r) * V_ + k);
    }

    const float bias_r = bih[g_r] + bhh[g_r];
    const float bias_z = bih[512 + g_r] + bhh[512 + g_r];
    const float bihn = bih[1024 + g_r];
    const float bhhn = bhh[1024 + g_r];

    int len4[4];
#pragma unroll
    for (int i = 0; i < 4; ++i) len4[i] = lenS[quad * 4 + i];
    const int maxlen = lenS[0];  // lengths sorted descending

    float h_own[4] = {0.f, 0.f, 0.f, 0.f};  // fp32 master state (b=quad*4+i, j=col)

    const _Float16* arh = &Ahi[col * RSTR + quad * 8];
    const _Float16* arl = &Alo[col * RSTR + quad * 8];

    for (int t = 0; t < S_; ++t) {
        if (t < maxlen) {
            const int par = t & 1;
            // ---- x prefetch (read-only; issue before barrier): 4 int4 ----
            int4 xv[4];
#pragma unroll
            for (int i = 0; i < 4; ++i) {
                int idx = tid + i * 128;      // 512 int4: b = idx>>5, v4 = (idx&31)*4
                int b = idx >> 5;
                int v4 = (idx & 31) * 4;
                int len = lenS[b];
                int sx = d ? max(0, len - 1 - t) : t;
                xv[i] = *(const int4*)(xp + ((size_t)(b0 + b) * S_ + sx) * V_ + v4);
            }
            // ---- chain barrier: all 16 wgs have written h(t) ----
            if (t > 0) {
                if (tid == 0) {
                    unsigned spins = 0;
                    while (__hip_atomic_load(&cnt[chain], __ATOMIC_ACQUIRE,
                                             __HIP_MEMORY_SCOPE_SYSTEM) < 16u * (unsigned)t) {
                        __builtin_amdgcn_s_sleep(8);
                        if (++spins > 300000000u) break;  // deadlock -> visible timeout
                    }
                }
                __syncthreads();
                fence_sys();  // acquire: invalidate stale L1/L2 lines
            }
            // ---- load packed h (parity buffer): 16 int4 ----
            const unsigned* hrp = hbuf + ((size_t)(par * 2 + d) * B_ + b0) * H_;
            int4 hv[16];
#pragma unroll
            for (int i = 0; i < 16; ++i) {
                int idx = tid + i * 128;      // 2048 int4: b = idx>>7, k4 = (idx&127)*4
                int b = idx >> 7;
                int k4 = (idx & 127) * 4;
                hv[i] = *(const int4*)(hrp + (size_t)b * H_ + k4);
            }
            // ---- unpack (hi,lo) and stage into LDS ----
#pragma unroll
            for (int i = 0; i < 4; ++i) {
                int idx = tid + i * 128;
                int b = idx >> 5;
                int v4 = (idx & 31) * 4;
                int4 w = xv[i];
                unsigned u0 = ((unsigned)w.x & 0xffffu) | ((unsigned)w.y << 16);
                unsigned u1 = ((unsigned)w.z & 0xffffu) | ((unsigned)w.w << 16);
                unsigned l0 = ((unsigned)w.x >> 16) | ((unsigned)w.y & 0xffff0000u);
                unsigned l1 = ((unsigned)w.z >> 16) | ((unsigned)w.w & 0xffff0000u);
                *(uint2*)&Ahi[b * RSTR + 512 + v4] = make_uint2(u0, u1);
                *(uint2*)&Alo[b * RSTR + 512 + v4] = make_uint2(l0, l1);
            }
#pragma unroll
            for (int i = 0; i < 16; ++i) {
                int idx = tid + i * 128;
                int b = idx >> 7;
                int k4 = (idx & 127) * 4;
                int4 w = hv[i];
                unsigned u0 = ((unsigned)w.x & 0xffffu) | ((unsigned)w.y << 16);
                unsigned u1 = ((unsigned)w.z & 0xffffu) | ((unsigned)w.w << 16);
                unsigned l0 = ((unsigned)w.x >> 16) | ((unsigned)w.y & 0xffff0000u);
                unsigned l1 = ((unsigned)w.z >> 16) | ((unsigned)w.w & 0xffff0000u);
                *(uint2*)&Ahi[b * RSTR + k4] = make_uint2(u0, u1);
                *(uint2*)&Alo[b * RSTR + k4] = make_uint2(l0, l1);
            }
            __syncthreads();

            // ---- MFMA: hw = (h_hi + h_lo) @ W^T (fp16 in, fp32 acc) ----
            f32x4 accr = {0.f, 0.f, 0.f, 0.f};
            f32x4 accz = {0.f, 0.f, 0.f, 0.f};
            f32x4 acchn = {0.f, 0.f, 0.f, 0.f};
            f32x4 accxn = {0.f, 0.f, 0.f, 0.f};
#pragma unroll
            for (int kk = 0; kk < 16; ++kk) {
                f16x8 ah = *(const f16x8*)(arh + kk * 32);
                f16x8 al = *(const f16x8*)(arl + kk * 32);
                accr = __builtin_amdgcn_mfma_f32_16x16x32_f16(ah, br[kk], accr, 0, 0, 0);
                accr = __builtin_amdgcn_mfma_f32_16x16x32_f16(al, br[kk], accr, 0, 0, 0);
                accz = __builtin_amdgcn_mfma_f32_16x16x32_f16(ah, bz[kk], accz, 0, 0, 0);
                accz = __builtin_amdgcn_mfma_f32_16x16x32_f16(al, bz[kk], accz, 0, 0, 0);
                acchn = __builtin_amdgcn_mfma_f32_16x16x32_f16(ah, bn[kk], acchn, 0, 0, 0);
                acchn = __builtin_amdgcn_mfma_f32_16x16x32_f16(al, bn[kk], acchn, 0, 0, 0);
            }
#pragma unroll
            for (int kk = 16; kk < 20; ++kk) {
                f16x8 ah = *(const f16x8*)(arh + 512 + (kk - 16) * 32);
                f16x8 al = *(const f16x8*)(arl + 512 + (kk - 16) * 32);
                accr = __builtin_amdgcn_mfma_f32_16x16x32_f16(ah, br[kk], accr, 0, 0, 0);
                accr = __builtin_amdgcn_mfma_f32_16x16x32_f16(al, br[kk], accr, 0, 0, 0);
                accz = __builtin_amdgcn_mfma_f32_16x16x32_f16(ah, bz[kk], accz, 0, 0, 0);
                accz = __builtin_amdgcn_mfma_f32_16x16x32_f16(al, bz[kk], accz, 0, 0, 0);
                accxn = __builtin_amdgcn_mfma_f32_16x16x32_f16(ah, bn[kk], accxn, 0, 0, 0);
                accxn = __builtin_amdgcn_mfma_f32_16x16x32_f16(al, bn[kk], accxn, 0, 0, 0);
            }

            // ---- gates + state update + stores (C layout: b=quad*4+i, j=col) ----
            unsigned* hwp = hbuf + ((size_t)((1 - par) * 2 + d) * B_ + b0) * H_;
#pragma unroll
            for (int i = 0; i < 4; ++i) {
                int bl = quad * 4 + i;
                float r = sigm(accr[i] + bias_r);
                float zg = sigm(accz[i] + bias_z);
                float ng = tanhf_((accxn[i] + bihn) + r * (acchn[i] + bhhn));
                float hcand = (1.0f - zg) * ng + zg * h_own[i];
                bool m = (t < len4[i]);
                float y = m ? hcand : 0.0f;
                h_own[i] = m ? hcand : h_own[i];
                _Float16 hhi = (_Float16)h_own[i];
                _Float16 hlo = (_Float16)(h_own[i] - (float)hhi);
                hwp[(size_t)bl * H_ + j0w + col] =
                    (unsigned)f16bits(hhi) | ((unsigned)f16bits(hlo) << 16);
                int s_out = (d && m) ? (len4[i] - 1 - t) : t;
                Ycat[((size_t)(b0 + bl) * S_ + s_out) * 1024 + d * 512 + j0w + col] = (_Float16)y;
            }
            fence_sys();  // release h(t+1): write back before arrival
            __syncthreads();
            if (tid == 0)
                __hip_atomic_fetch_add(&cnt[chain], 1u, __ATOMIC_RELEASE, __HIP_MEMORY_SCOPE_SYSTEM);
        } else {
            // whole group masked: zeros at s_out = t; no barrier traffic
#pragma unroll
            for (int i = 0; i < 4; ++i) {
                int bl = quad * 4 + i;
                Ycat[((size_t)(b0 + bl) * S_ + t) * 1024 + d * 512 + j0w + col] = (_Float16)0.0f;
            }
        }
    }
}

// Final linear: out[b,s,l] = b_lin[l] + sum_c Ycat[b,s,c] * Wf[l,c]  (fp32 out)
__global__ void lin_kernel(const _Float16* __restrict__ Ycat, const float* __restrict__ Wf,
                           const float* __restrict__ blinF, float* __restrict__ out) {
    int tid = threadIdx.x;
    int p_loc = tid >> 4, lq = tid & 15;
    int pos = blockIdx.x * 16 + p_loc;
    const _Float16* yrow = Ycat + (size_t)pos * 1024;
    int l0 = lq * 4;
    const float* w0 = Wf + (size_t)(l0 + 0) * 1024;
    const float* w1 = Wf + (size_t)(l0 + 1) * 1024;
    const float* w2 = Wf + (size_t)(l0 + 2) * 1024;
    const float* w3 = Wf + (size_t)(l0 + 3) * 1024;
    float a0 = 0.f, a1 = 0.f, a2 = 0.f, a3 = 0.f;
    for (int c = 0; c < 1024; c += 8) {
        f16x8 y8 = *(const f16x8*)(yrow + c);
#pragma unroll
        for (int e = 0; e < 8; ++e) {
            float y = (float)y8[e];
            a0 = fmaf(y, w0[c + e], a0);
            a1 = fmaf(y, w1[c + e], a1);
            a2 = fmaf(y, w2[c + e], a2);
            a3 = fmaf(y, w3[c + e], a3);
        }
    }
    size_t ob = (size_t)pos * L_ + l0;
    out[ob + 0] = a0 + blinF[l0 + 0];
    out[ob + 1] = a1 + blinF[l0 + 1];
    out[ob + 2] = a2 + blinF[l0 + 2];
    out[ob + 3] = a3 + blinF[l0 + 3];
}

extern "C" void kernel_launch(void* const* d_in, const int* in_sizes, int n_in,
                              void* d_out, int out_size, void* d_ws, size_t ws_size,
                              hipStream_t stream) {
    const int* chars = (const int*)d_in[0];
    const int* lengths = (const int*)d_in[1];
    const void* forget = d_in[2];
    const void* Wihf = d_in[3];
    const void* Whhf = d_in[4];
    const void* bihf = d_in[5];
    const void* bhhf = d_in[6];
    const void* Wihb = d_in[7];
    const void* Whhb = d_in[8];
    const void* bihb = d_in[9];
    const void* bhhb = d_in[10];
    const void* Wlin = d_in[11];
    const void* blin = d_in[12];
    float* out = (float*)d_out;

    char* ws = (char*)d_ws;
    unsigned* hbuf = (unsigned*)(ws + 0);
    unsigned* cnt = (unsigned*)(ws + OFF_CNT);
    int* flag = (int*)(ws + OFF_FLAG);
    unsigned* xp = (unsigned*)(ws + OFF_X);
    _Float16* whalf = (_Float16*)(ws + OFF_WH);
    float* smallF = (float*)(ws + OFF_SMALL);
    _Float16* Ycat = (_Float16*)(ws + OFF_YCAT);

    // zero h state (both parities) + chain counters + flag
    (void)hipMemsetAsync(ws, 0, OFF_X, stream);

    hipLaunchKernelGGL(detect_kernel, dim3(1), dim3(256), 0, stream,
                       (const unsigned*)Whhf, flag);
    hipLaunchKernelGGL(prep_whalf, dim3(1966080 / 256), dim3(256), 0, stream,
                       Whhf, Whhb, Wihf, Wihb, whalf, flag);
    hipLaunchKernelGGL(prep_small, dim3(281), dim3(256), 0, stream,
                       bihf, bhhf, bihb, bhhb, Wlin, blin, forget, smallF, flag);
    hipLaunchKernelGGL(fofe_kernel, dim3(B_ * S_), dim3(V_), 0, stream,
                       chars, smallF + 71744, xp);

    // PLAIN launch (not cooperative): sync is hand-rolled system-scope atomics,
    // grid 256 == CU count so all blocks resident by capacity.
    hipLaunchKernelGGL(gru_kernel, dim3(256), dim3(128), 0, stream,
                       lengths, whalf, smallF, xp, hbuf, cnt, Ycat);

    hipLaunchKernelGGL(lin_kernel, dim3(B_ * S_ / 16), dim3(256), 0, stream,
                       Ycat, smallF + 6144, smallF + 71680, out);
}

// Round 7
// 1347.972 us; speedup vs baseline: 2.8913x; 2.8913x over previous
//
#include <hip/hip_runtime.h>
#include <hip/hip_bf16.h>

// Problem constants
#define B_ 128
#define S_ 128
#define W_ 16
#define V_ 128
#define H_ 512
#define L_ 64

typedef _Float16 f16x8 __attribute__((ext_vector_type(8)));
typedef float f32x4 __attribute__((ext_vector_type(4)));

__device__ __forceinline__ float sigm(float v) { return 1.0f / (1.0f + __expf(-v)); }
__device__ __forceinline__ float tanhf_(float v) { return 1.0f - 2.0f / (1.0f + __expf(2.0f * v)); }

__device__ __forceinline__ unsigned short f16bits(_Float16 h) {
    return __builtin_bit_cast(unsigned short, h);
}

// ---------------------------------------------------------------------------
// Workspace layout (bytes):
//   hbhi  u16 [par2][dir2][128][512]  @ 0        (524288)   h high-halves
//   hblo  u16 [par2][dir2][128][512]  @ 524288   (524288)   h low-halves
//   cnt   u32 [16][32] (128B/chain)   @ 1048576  (2048)     padded spin lines
//   flag  i32                         @ 1050624  (64)
//   xhi   u16 [128][128][128]         @ 1050688  (4194304)
//   xlo   u16 [128][128][128]         @ 5244992  (4194304)
//   whalf f16 [1966080]               @ 9439296  (3932160)
//         [whhf 786432 | whhb 786432 | wihf 196608 | wihb 196608]
//   smallF f32 [71745]                @ 13371456 (286980)
//         [bihf 1536|bhhf 1536|bihb 1536|bhhb 1536|wlin 65536|blin 64|fg 1]
//   Ycat  f16 [128][128][1024]        @ 13658624 (33554432) -> ends 47213056
// ---------------------------------------------------------------------------
#define OFF_HBLO  524288
#define OFF_CNT   1048576
#define OFF_FLAG  1050624
#define OFF_XHI   1050688
#define OFF_XLO   5244992
#define OFF_WH    9439296
#define OFF_SMALL 13371456
#define OFF_YCAT  13658624

// Runtime input-dtype detection (insurance): low-16 exponent-field vote.
__global__ void detect_kernel(const unsigned* __restrict__ w, int* __restrict__ flag) {
    __shared__ int sv[256];
    int tid = threadIdx.x;
    unsigned word = w[tid];
    unsigned e = (word >> 7) & 0xFFu;
    sv[tid] = (e >= 64u && e <= 126u) ? 1 : 0;
    __syncthreads();
    for (int s = 128; s > 0; s >>= 1) {
        if (tid < s) sv[tid] += sv[tid + s];
        __syncthreads();
    }
    if (tid == 0) *flag = (sv[0] >= 160) ? 1 : 0;  // 1 = inputs are bf16
}

// Canonicalize the 4 big weight matrices into packed fp16 (RTN) in ws.
__global__ void prep_whalf(const void* __restrict__ whhf, const void* __restrict__ whhb,
                           const void* __restrict__ wihf, const void* __restrict__ wihb,
                           _Float16* __restrict__ dst, const int* __restrict__ flag) {
    int i = blockIdx.x * 256 + threadIdx.x;  // grid covers 1966080 exactly
    const void* src;
    int off;
    if (i < 786432)       { src = whhf; off = i; }
    else if (i < 1572864) { src = whhb; off = i - 786432; }
    else if (i < 1769472) { src = wihf; off = i - 1572864; }
    else                  { src = wihb; off = i - 1769472; }
    float v = (*flag) ? __bfloat162float(((const __hip_bfloat16*)src)[off])
                      : ((const float*)src)[off];
    dst[i] = (_Float16)v;
}

// Canonicalize biases + W_lin + b_lin + forget into fp32 in ws.
__global__ void prep_small(const void* __restrict__ bihf, const void* __restrict__ bhhf,
                           const void* __restrict__ bihb, const void* __restrict__ bhhb,
                           const void* __restrict__ wlin, const void* __restrict__ blin,
                           const void* __restrict__ fg,
                           float* __restrict__ dst, const int* __restrict__ flag) {
    int i = blockIdx.x * 256 + threadIdx.x;
    if (i >= 71745) return;
    const void* src;
    int off;
    if (i < 1536)       { src = bihf; off = i; }
    else if (i < 3072)  { src = bhhf; off = i - 1536; }
    else if (i < 4608)  { src = bihb; off = i - 3072; }
    else if (i < 6144)  { src = bhhb; off = i - 4608; }
    else if (i < 71680) { src = wlin; off = i - 6144; }
    else if (i < 71744) { src = blin; off = i - 71680; }
    else                { src = fg;   off = 0; }
    float v = (*flag) ? __bfloat162float(((const __hip_bfloat16*)src)[off])
                      : ((const float*)src)[off];
    dst[i] = v;
}

// FOFE -> split hi/lo fp16 planes.
__global__ void fofe_kernel(const int* __restrict__ chars,
                            const float* __restrict__ fg,
                            unsigned short* __restrict__ xhi,
                            unsigned short* __restrict__ xlo) {
    __shared__ int cS[W_];
    int bi = blockIdx.x;  // b*S + s
    int tid = threadIdx.x;
    if (tid < W_) cS[tid] = chars[bi * W_ + tid];
    __syncthreads();
    float f = fg[0];
    float wt[W_];
    float cur = 1.0f;
#pragma unroll
    for (int w = W_ - 1; w >= 0; --w) {
        bool m = (cS[w] != 0);
        wt[w] = m ? cur : 0.0f;
        if (m) cur *= f;
    }
    int v = tid;  // blockDim = 128 = V_
    float acc = 0.0f;
#pragma unroll
    for (int w = 0; w < W_; ++w) acc += (cS[w] == v) ? wt[w] : 0.0f;
    _Float16 hi = (_Float16)acc;
    _Float16 lo = (_Float16)(acc - (float)hi);
    xhi[(size_t)bi * V_ + v] = f16bits(hi);
    xlo[(size_t)bi * V_ + v] = f16bits(lo);
}

// ---------------------------------------------------------------------------
// Persistent bidirectional GRU, fp16 hi/lo, fp32 accumulate.
// 16 chains x 8 blocks x 256 thr (4 waves). chain = blockIdx&15: a chain's
// blocks are {c, c+16, ...} -> all on ONE XCD under %8 round-robin dispatch.
// Wave owns 16 j x 3 gates; weights persistent in VGPRs. h exchange is
// fence-free: relaxed agent-scope atomic u16 stores (write-through) + relaxed
// agent-scope atomic u64 loads (cache-bypass). tid0 ACQUIRE spin on a padded
// per-chain counter line; one RELEASE fetch_add per block per step.
// ---------------------------------------------------------------------------
__launch_bounds__(256, 1)
__global__ void gru_kernel(const int* __restrict__ lengths,
                           const _Float16* __restrict__ wh,
                           const float* __restrict__ biasF,
                           const unsigned short* __restrict__ xhi,
                           const unsigned short* __restrict__ xlo,
                           unsigned short* __restrict__ hbhi,
                           unsigned short* __restrict__ hblo,
                           unsigned* __restrict__ cnt,
                           _Float16* __restrict__ Ycat) {
    constexpr int RSTR = 656;  // 640 + 16 pad halves (0 conflicts measured r5)
    __shared__ _Float16 Ahi[16 * RSTR];
    __shared__ _Float16 Alo[16 * RSTR];
    __shared__ int lenS[16];

    const int tid = threadIdx.x;
    const int chain = blockIdx.x & 15;
    const int slice = blockIdx.x >> 4;  // 0..7
    const int d = chain & 1;
    const int bg = chain >> 1;
    const int b0 = bg * 16;
    const int wave = tid >> 6;
    const int lane = tid & 63;
    const int quad = lane >> 4;
    const int col = lane & 15;
    const int j0w = (slice * 4 + wave) * 16;  // 0..496

    const _Float16* Whh = wh + (d ? 786432 : 0);
    const _Float16* Wih = wh + 1572864 + (d ? 196608 : 0);
    const float* bih = biasF + (d ? 3072 : 0);
    const float* bhh = biasF + 1536 + (d ? 3072 : 0);

    if (tid < 16) lenS[tid] = lengths[b0 + tid];
    __syncthreads();

    const int g_r = j0w + col;  // r row; z = 512+g_r; n = 1024+g_r

    // Persistent B fragments: lane holds W[g][kk*32 + quad*8 + 0..7]
    f16x8 br[20], bz[20], bn[20];
#pragma unroll
    for (int kk = 0; kk < 16; ++kk) {
        int k = kk * 32 + quad * 8;
        br[kk] = *(const f16x8*)(Whh + (size_t)(g_r)*H_ + k);
        bz[kk] = *(const f16x8*)(Whh + (size_t)(512 + g_r) * H_ + k);
        bn[kk] = *(const f16x8*)(Whh + (size_t)(1024 + g_r) * H_ + k);
    }
#pragma unroll
    for (int kk = 16; kk < 20; ++kk) {
        int k = (kk - 16) * 32 + quad * 8;
        br[kk] = *(const f16x8*)(Wih + (size_t)(g_r)*V_ + k);
        bz[kk] = *(const f16x8*)(Wih + (size_t)(512 + g_r) * V_ + k);
        bn[kk] = *(const f16x8*)(Wih + (size_t)(1024 + g_r) * V_ + k);
    }

    const float bias_r = bih[g_r] + bhh[g_r];
    const float bias_z = bih[512 + g_r] + bhh[512 + g_r];
    const float bihn = bih[1024 + g_r];
    const float bhhn = bhh[1024 + g_r];

    int len4[4];
#pragma unroll
    for (int i = 0; i < 4; ++i) len4[i] = lenS[quad * 4 + i];
    const int maxlen = lenS[0];  // lengths sorted descending

    float h_own[4] = {0.f, 0.f, 0.f, 0.f};  // fp32 master state (b=quad*4+i, j=col)

    const _Float16* arh = &Ahi[col * RSTR + quad * 8];
    const _Float16* arl = &Alo[col * RSTR + quad * 8];

    // x staging: 16 rows x 16 chunks of 8 halves (int4 = 16B = 8 halves)
    const int xb = tid >> 4;
    const int xv8 = (tid & 15) * 8;

    for (int t = 0; t < S_; ++t) {
        if (t < maxlen) {
            const int par = t & 1;
            // ---- x loads (plain cached, RO; issued before barrier) ----
            int lxb = lenS[xb];
            int sxb = d ? max(0, lxb - 1 - t) : t;
            int4 xh4 = *(const int4*)(xhi + ((size_t)(b0 + xb) * S_ + sxb) * V_ + xv8);
            int4 xl4 = *(const int4*)(xlo + ((size_t)(b0 + xb) * S_ + sxb) * V_ + xv8);
            // ---- chain barrier: all 8 blocks posted step t-1 ----
            if (t > 0) {
                if (tid == 0) {
                    unsigned spins = 0;
                    while (__hip_atomic_load(&cnt[chain * 32], __ATOMIC_ACQUIRE,
                                             __HIP_MEMORY_SCOPE_AGENT) < 8u * (unsigned)t) {
                        __builtin_amdgcn_s_sleep(1);
                        if (++spins > 100000000u) break;  // deadlock -> visible timeout
                    }
                }
                __syncthreads();  // join spin + WAR (step t-1 LDS reads done)
            }
            // ---- h loads: cache-bypass u64 atomics, 4-half granularity ----
            // 2048 chunks/plane = 16 rows x 128 chunks(4 halves); 8 per thread
            const unsigned short* hrh = hbhi + ((size_t)(par * 2 + d) * B_ + b0) * H_;
            const unsigned short* hrl = hblo + ((size_t)(par * 2 + d) * B_ + b0) * H_;
            unsigned long long hh[8], hl[8];
#pragma unroll
            for (int i = 0; i < 8; ++i) {
                int c = tid + i * 256;
                int b = c >> 7;
                int k4 = (c & 127) * 4;
                hh[i] = __hip_atomic_load((const unsigned long long*)(hrh + (size_t)b * H_ + k4),
                                          __ATOMIC_RELAXED, __HIP_MEMORY_SCOPE_AGENT);
                hl[i] = __hip_atomic_load((const unsigned long long*)(hrl + (size_t)b * H_ + k4),
                                          __ATOMIC_RELAXED, __HIP_MEMORY_SCOPE_AGENT);
            }
            // ---- stage into LDS ----
            *(int4*)&Ahi[xb * RSTR + 512 + xv8] = xh4;
            *(int4*)&Alo[xb * RSTR + 512 + xv8] = xl4;
#pragma unroll
            for (int i = 0; i < 8; ++i) {
                int c = tid + i * 256;
                int b = c >> 7;
                int k4 = (c & 127) * 4;
                *(unsigned long long*)&Ahi[b * RSTR + k4] = hh[i];
                *(unsigned long long*)&Alo[b * RSTR + k4] = hl[i];
            }
            __syncthreads();

            // ---- MFMA: hw = (h_hi + h_lo) @ W^T (fp16 in, fp32 acc) ----
            f32x4 accr = {0.f, 0.f, 0.f, 0.f};
            f32x4 accz = {0.f, 0.f, 0.f, 0.f};
            f32x4 acchn = {0.f, 0.f, 0.f, 0.f};
            f32x4 accxn = {0.f, 0.f, 0.f, 0.f};
#pragma unroll
            for (int kk = 0; kk < 16; ++kk) {
                f16x8 ah = *(const f16x8*)(arh + kk * 32);
                f16x8 al = *(const f16x8*)(arl + kk * 32);
                accr = __builtin_amdgcn_mfma_f32_16x16x32_f16(ah, br[kk], accr, 0, 0, 0);
                accr = __builtin_amdgcn_mfma_f32_16x16x32_f16(al, br[kk], accr, 0, 0, 0);
                accz = __builtin_amdgcn_mfma_f32_16x16x32_f16(ah, bz[kk], accz, 0, 0, 0);
                accz = __builtin_amdgcn_mfma_f32_16x16x32_f16(al, bz[kk], accz, 0, 0, 0);
                acchn = __builtin_amdgcn_mfma_f32_16x16x32_f16(ah, bn[kk], acchn, 0, 0, 0);
                acchn = __builtin_amdgcn_mfma_f32_16x16x32_f16(al, bn[kk], acchn, 0, 0, 0);
            }
#pragma unroll
            for (int kk = 16; kk < 20; ++kk) {
                f16x8 ah = *(const f16x8*)(arh + 512 + (kk - 16) * 32);
                f16x8 al = *(const f16x8*)(arl + 512 + (kk - 16) * 32);
                accr = __builtin_amdgcn_mfma_f32_16x16x32_f16(ah, br[kk], accr, 0, 0, 0);
                accr = __builtin_amdgcn_mfma_f32_16x16x32_f16(al, br[kk], accr, 0, 0, 0);
                accz = __builtin_amdgcn_mfma_f32_16x16x32_f16(ah, bz[kk], accz, 0, 0, 0);
                accz = __builtin_amdgcn_mfma_f32_16x16x32_f16(al, bz[kk], accz, 0, 0, 0);
                accxn = __builtin_amdgcn_mfma_f32_16x16x32_f16(ah, bn[kk], accxn, 0, 0, 0);
                accxn = __builtin_amdgcn_mfma_f32_16x16x32_f16(al, bn[kk], accxn, 0, 0, 0);
            }

            // ---- gates + state update + stores (C layout: b=quad*4+i, j=col) ----
            unsigned short* hwh = hbhi + ((size_t)((1 - par) * 2 + d) * B_ + b0) * H_;
            unsigned short* hwl = hblo + ((size_t)((1 - par) * 2 + d) * B_ + b0) * H_;
#pragma unroll
            for (int i = 0; i < 4; ++i) {
                int bl = quad * 4 + i;
                float r = sigm(accr[i] + bias_r);
                float zg = sigm(accz[i] + bias_z);
                float ng = tanhf_((accxn[i] + bihn) + r * (acchn[i] + bhhn));
                float hcand = (1.0f - zg) * ng + zg * h_own[i];
                bool m = (t < len4[i]);
                float y = m ? hcand : 0.0f;
                h_own[i] = m ? hcand : h_own[i];
                _Float16 hhi = (_Float16)h_own[i];
                _Float16 hlo = (_Float16)(h_own[i] - (float)hhi);
                __hip_atomic_store(hwh + (size_t)bl * H_ + j0w + col, f16bits(hhi),
                                   __ATOMIC_RELAXED, __HIP_MEMORY_SCOPE_AGENT);
                __hip_atomic_store(hwl + (size_t)bl * H_ + j0w + col, f16bits(hlo),
                                   __ATOMIC_RELAXED, __HIP_MEMORY_SCOPE_AGENT);
                int s_out = (d && m) ? (len4[i] - 1 - t) : t;
                Ycat[((size_t)(b0 + bl) * S_ + s_out) * 1024 + d * 512 + j0w + col] = (_Float16)y;
            }
            __syncthreads();  // emits s_waitcnt vmcnt(0): h stores at coherence pt
            if (tid == 0)
                __hip_atomic_fetch_add(&cnt[chain * 32], 1u, __ATOMIC_RELEASE,
                                       __HIP_MEMORY_SCOPE_AGENT);
        } else {
            // whole group masked: zeros at s_out = t; no barrier traffic
#pragma unroll
            for (int i = 0; i < 4; ++i) {
                int bl = quad * 4 + i;
                Ycat[((size_t)(b0 + bl) * S_ + t) * 1024 + d * 512 + j0w + col] = (_Float16)0.0f;
            }
        }
    }
}

// Final linear: out[b,s,l] = b_lin[l] + sum_c Ycat[b,s,c] * Wf[l,c]  (fp32 out)
__global__ void lin_kernel(const _Float16* __restrict__ Ycat, const float* __restrict__ Wf,
                           const float* __restrict__ blinF, float* __restrict__ out) {
    int tid = threadIdx.x;
    int p_loc = tid >> 4, lq = tid & 15;
    int pos = blockIdx.x * 16 + p_loc;
    const _Float16* yrow = Ycat + (size_t)pos * 1024;
    int l0 = lq * 4;
    const float* w0 = Wf + (size_t)(l0 + 0) * 1024;
    const float* w1 = Wf + (size_t)(l0 + 1) * 1024;
    const float* w2 = Wf + (size_t)(l0 + 2) * 1024;
    const float* w3 = Wf + (size_t)(l0 + 3) * 1024;
    float a0 = 0.f, a1 = 0.f, a2 = 0.f, a3 = 0.f;
    for (int c = 0; c < 1024; c += 8) {
        f16x8 y8 = *(const f16x8*)(yrow + c);
#pragma unroll
        for (int e = 0; e < 8; ++e) {
            float y = (float)y8[e];
            a0 = fmaf(y, w0[c + e], a0);
            a1 = fmaf(y, w1[c + e], a1);
            a2 = fmaf(y, w2[c + e], a2);
            a3 = fmaf(y, w3[c + e], a3);
        }
    }
    size_t ob = (size_t)pos * L_ + l0;
    out[ob + 0] = a0 + blinF[l0 + 0];
    out[ob + 1] = a1 + blinF[l0 + 1];
    out[ob + 2] = a2 + blinF[l0 + 2];
    out[ob + 3] = a3 + blinF[l0 + 3];
}

extern "C" void kernel_launch(void* const* d_in, const int* in_sizes, int n_in,
                              void* d_out, int out_size, void* d_ws, size_t ws_size,
                              hipStream_t stream) {
    const int* chars = (const int*)d_in[0];
    const int* lengths = (const int*)d_in[1];
    const void* forget = d_in[2];
    const void* Wihf = d_in[3];
    const void* Whhf = d_in[4];
    const void* bihf = d_in[5];
    const void* bhhf = d_in[6];
    const void* Wihb = d_in[7];
    const void* Whhb = d_in[8];
    const void* bihb = d_in[9];
    const void* bhhb = d_in[10];
    const void* Wlin = d_in[11];
    const void* blin = d_in[12];
    float* out = (float*)d_out;

    char* ws = (char*)d_ws;
    unsigned short* hbhi = (unsigned short*)(ws + 0);
    unsigned short* hblo = (unsigned short*)(ws + OFF_HBLO);
    unsigned* cnt = (unsigned*)(ws + OFF_CNT);
    int* flag = (int*)(ws + OFF_FLAG);
    unsigned short* xhi = (unsigned short*)(ws + OFF_XHI);
    unsigned short* xlo = (unsigned short*)(ws + OFF_XLO);
    _Float16* whalf = (_Float16*)(ws + OFF_WH);
    float* smallF = (float*)(ws + OFF_SMALL);
    _Float16* Ycat = (_Float16*)(ws + OFF_YCAT);

    // zero h state (both parities, hi+lo) + chain counters + flag
    (void)hipMemsetAsync(ws, 0, OFF_XHI, stream);

    hipLaunchKernelGGL(detect_kernel, dim3(1), dim3(256), 0, stream,
                       (const unsigned*)Whhf, flag);
    hipLaunchKernelGGL(prep_whalf, dim3(1966080 / 256), dim3(256), 0, stream,
                       Whhf, Whhb, Wihf, Wihb, whalf, flag);
    hipLaunchKernelGGL(prep_small, dim3(281), dim3(256), 0, stream,
                       bihf, bhhf, bihb, bhhb, Wlin, blin, forget, smallF, flag);
    hipLaunchKernelGGL(fofe_kernel, dim3(B_ * S_), dim3(V_), 0, stream,
                       chars, smallF + 71744, xhi, xlo);

    // 16 chains x 8 blocks x 256 threads; hand-rolled agent-scope sync.
    hipLaunchKernelGGL(gru_kernel, dim3(128), dim3(256), 0, stream,
                       lengths, whalf, smallF, xhi, xlo, hbhi, hblo, cnt, Ycat);

    hipLaunchKernelGGL(lin_kernel, dim3(B_ * S_ / 16), dim3(256), 0, stream,
                       Ycat, smallF + 6144, smallF + 71680, out);
}